// Round 13
// baseline (317.182 us; speedup 1.0000x reference)
//
#include <hip/hip_runtime.h>

// FireLSTM: x[8192,512,4] fp32 -> LSTM(H=64) -> FC(64->1), out[8192] fp32.
//
// R13: LOCKSTEP co-resident waves. 256 blocks x 512 thr (8 waves) = 1
// block/CU, 2 waves/SIMD -- both waves on a SIMD belong to the SAME block and
// hit the SAME barrier (R12 had 2 independent blocks/CU whose heads landed at
// uncorrelated times: ~690 cyc/step idle). Block owns 32 batches as TWO
// independent groups of 16; waves 0-3 = G0 h-quarters, waves 4-7 = G1.
// Per-wave program identical to R12: 12x mfma_f32_16x16x32_f16 (4 tiles x
// K=96=[h|x+bias|pad], full M=16), 4 register-local cells, 28 trans. ONE
// shared barrier/step orders each group's h write->read. Mechanism: the
// post-barrier head (ds_read h + MFMA chain, ~300 cyc) is exposed ONCE per
// step (both waves stall together), then the two trans phases serialize
// through the trans pipe -- which IS the 896 cyc/SIMD/step trans-issue floor.
//
// Kept from R12: packed-f32 cell algebra (f32x2 pk ops), x-slice prefetch
// across the barrier, single-sided clamp, 7-trans merged-rcp cell update,
// k-slot bias (68,69 vs A=1.0), zero-C operand, raw lgkm-only step barrier
// (vmcnt never drained), double-buffered fp16x4 x staging, MFMA-only setprio.
// Dropped: s_sleep anti-phase (lockstep is the point now).

typedef float f32x4 __attribute__((ext_vector_type(4)));
typedef float f32x2 __attribute__((ext_vector_type(2)));
typedef _Float16 f16x8 __attribute__((ext_vector_type(8)));
typedef _Float16 f16x4 __attribute__((ext_vector_type(4)));

#define TSEQ 512
#define IDIM 4
#define BPB 32              // 2 groups x 16 batches
#define TCH 32
#define NCH (TSEQ / TCH)
#define L2E 1.44269504088896340736f

#if __has_builtin(__builtin_amdgcn_exp2f)
#define EX2(v) __builtin_amdgcn_exp2f(v)
#else
#define EX2(v) exp2f(v)
#endif
#define RCP(v) __builtin_amdgcn_rcpf(v)

// lgkmcnt(0) makes our ds_writes visible; s_barrier rendezvous. No vmcnt
// drain (x prefetch floats free); no sched_barrier (m141: order-pinning).
#define STEP_BARRIER() do {                                   \
    asm volatile("s_waitcnt lgkmcnt(0)" ::: "memory");        \
    __builtin_amdgcn_s_barrier();                             \
} while (0)

__global__ __launch_bounds__(512, 1) void lstm_fused(
    const float* __restrict__ x,
    const float* __restrict__ W_ih,
    const float* __restrict__ W_hh,
    const float* __restrict__ b_ih,
    const float* __restrict__ b_hh,
    const float* __restrict__ W_fc,
    const float* __restrict__ b_fc,
    float* __restrict__ out)
{
    __shared__ __align__(16) _Float16 hbuf[2][2][16 * 64];    // [parity][group], 8 KB
    __shared__ __align__(16) f16x4    xstage[2][2][16][33];   // [group][buf], 16.9 KB

    const int tid  = threadIdx.x;
    const int lane = tid & 63;
    const int wvl  = (tid >> 6) & 3;   // h-quarter within the group team
    const int grp  = tid >> 8;         // 0 = G0 (waves 0-3), 1 = G1 (waves 4-7)
    const int b0   = blockIdx.x * BPB;
    const int r    = lane & 15;
    const int g16  = lane >> 4;

    // ---- B-fragments: 4 types x K=96, pre-scaled. k = ks*32 + 8*g16 + j.
    // ks=2: k=64..67 -> W_ih, k=68,69 -> bias hi/lo (vs A=1.0), k>=70 -> 0.
    f16x8 bfrag[4][3];
    #pragma unroll
    for (int t4 = 0; t4 < 4; ++t4) {
        const float sc = (t4 == 2) ? 2.0f * L2E : L2E;
        const int g = t4 * 64 + wvl * 16 + r;
        #pragma unroll
        for (int ks = 0; ks < 2; ++ks) {
            const float* p = W_hh + g * 64 + ks * 32 + g16 * 8;
            f16x8 f;
            #pragma unroll
            for (int j = 0; j < 8; ++j) f[j] = (_Float16)(p[j] * sc);
            bfrag[t4][ks] = f;
        }
        f16x8 f;
        #pragma unroll
        for (int j = 0; j < 8; ++j) f[j] = (_Float16)0.0f;
        if (g16 == 0) {
            #pragma unroll
            for (int j = 0; j < 4; ++j) f[j] = (_Float16)(W_ih[g * IDIM + j] * sc);
            float biasf = (b_ih[g] + b_hh[g]) * sc;
            _Float16 hi = (_Float16)biasf;
            f[4] = hi;
            f[5] = (_Float16)(biasf - (float)hi);
        }
        bfrag[t4][2] = f;
    }
    const float wfc = W_fc[lane];
    const float bfc = b_fc[0];
    const f32x4 zero4 = {0.f, 0.f, 0.f, 0.f};

    float c_reg[4] = {0.f, 0.f, 0.f, 0.f};
    // zero parity 0, both groups (flat elems 0..2047 of [2][2][1024])
    for (int i = tid; i < 2 * 16 * 64; i += 512)
        ((_Float16*)&hbuf[0][0][0])[i] = (_Float16)0.0f;

    // ---- x: thread loads G0 row bb0 and G1 row bb0 at chunk-step tf ----
    const int bb0 = tid >> 5, tf = tid & 31;   // bb0: 0..15
    const float* xg0 = x + ((size_t)(b0 + bb0)      * TSEQ + tf) * IDIM;  // G0
    const float* xg1 = x + ((size_t)(b0 + 16 + bb0) * TSEQ + tf) * IDIM;  // G1
    float4 xn0 = *(const float4*)xg0;
    float4 xn1 = *(const float4*)xg1;
    // stage chunk 0 into buf 0 of each group
    {
        f16x4 s0, s1;
        s0[0] = (_Float16)xn0.x; s0[1] = (_Float16)xn0.y;
        s0[2] = (_Float16)xn0.z; s0[3] = (_Float16)xn0.w;
        s1[0] = (_Float16)xn1.x; s1[1] = (_Float16)xn1.y;
        s1[2] = (_Float16)xn1.z; s1[3] = (_Float16)xn1.w;
        xstage[0][0][bb0][tf] = s0;
        xstage[1][0][bb0][tf] = s1;
    }
    __syncthreads();                       // once; chunk-1 loads issued after
    xn0 = *(const float4*)(xg0 + TCH * IDIM);
    xn1 = *(const float4*)(xg1 + TCH * IDIM);

    // ---- precomputed LDS byte offsets (within this wave's group) ----
    const int hbase = r * 128;
    const int hs0 = ((g16 + 0) << 4) ^ ((r & 7) << 4);
    const int hs1 = ((g16 + 4) << 4) ^ ((r & 7) << 4);
    int hw[4];
    #pragma unroll
    for (int q = 0; q < 4; ++q) {
        const int bat = 4 * g16 + q;
        hw[q] = (bat * 128 + (wvl * 16 + r) * 2) ^ ((bat & 7) << 4);
    }
    // hbuf layout: base + parity*4096 + grp*2048
    char* hbG = (char*)&hbuf[0][0][0] + grp * 2048;
    const char* xsB = (const char*)&xstage[grp][0][0][0];   // [buf][row][step]
    const int xrow = r * 33 * 8;           // row-r byte offset within one buf

    // x slice for step 0 (prefetched; subsequent slices loaded pre-barrier)
    f16x4 xv = *(const f16x4*)(xsB + xrow);

    // packed-f32 update for a cell pair (q0,q1): pk ops + 7x2 scalar trans
    auto cellpair = [&](const f32x4* acc, int q0, int q1, char* wb) {
        f32x2 ei, ef, eg, eo;
        ei[0] = EX2(-acc[0][q0]); ei[1] = EX2(-acc[0][q1]);
        ef[0] = EX2(-acc[1][q0]); ef[1] = EX2(-acc[1][q1]);
        eg[0] = EX2(-acc[2][q0]); eg[1] = EX2(-acc[2][q1]);
        eo[0] = EX2(-acc[3][q0]); eo[1] = EX2(-acc[3][q1]);
        const f32x2 one = {1.f, 1.f};
        f32x2 A  = one + ei, F = one + ef;
        f32x2 Gp = one + eg, Gm = one - eg;
        f32x2 P2 = A * Gp;
        f32x2 cr = { c_reg[q0], c_reg[q1] };
        f32x2 num = cr * P2 + Gm * F;          // v_pk_fma (contract)
        f32x2 den = P2 * F;
        f32x2 rd; rd[0] = RCP(den[0]); rd[1] = RCP(den[1]);
        f32x2 c = num * rd;
        c_reg[q0] = c[0]; c_reg[q1] = c[1];
        f32x2 uc = c * (2.0f * L2E);
        uc = __builtin_elementwise_max(uc, f32x2{-60.f, -60.f});  // lower clamp only
        f32x2 et; et[0] = EX2(-uc[0]); et[1] = EX2(-uc[1]);
        f32x2 hd = (one + eo) * (one + et);
        f32x2 rh; rh[0] = RCP(hd[0]); rh[1] = RCP(hd[1]);
        f32x2 h = (one - et) * rh;
        *(_Float16*)(wb + hw[q0]) = (_Float16)h[0];
        *(_Float16*)(wb + hw[q1]) = (_Float16)h[1];
    };

    // one sub-step; P = parity of t (compile-time)
    auto substep = [&](int t, int P) {
        const char* rb = hbG + P * 4096;         // h_{t-1} (this group)
        char*       wb = hbG + (P ^ 1) * 4096;   // h_t
        f16x8 a0 = *(const f16x8*)(rb + hbase + hs0);
        f16x8 a1 = *(const f16x8*)(rb + hbase + hs1);
        f16x8 ax;
        ax[0] = xv[0]; ax[1] = xv[1]; ax[2] = xv[2]; ax[3] = xv[3];
        ax[4] = (_Float16)1.0f; ax[5] = (_Float16)1.0f;   // bias slots (k=68,69)
        ax[6] = (_Float16)0.0f; ax[7] = (_Float16)0.0f;

        f32x4 acc[4];
        __builtin_amdgcn_s_setprio(1);
        #pragma unroll
        for (int t4 = 0; t4 < 4; ++t4) {
            f32x4 a;
            a = __builtin_amdgcn_mfma_f32_16x16x32_f16(a0, bfrag[t4][0], zero4, 0, 0, 0);
            a = __builtin_amdgcn_mfma_f32_16x16x32_f16(a1, bfrag[t4][1], a, 0, 0, 0);
            a = __builtin_amdgcn_mfma_f32_16x16x32_f16(ax, bfrag[t4][2], a, 0, 0, 0);
            acc[t4] = a;
        }
        __builtin_amdgcn_s_setprio(0);

        // prefetch NEXT step's x slice (no dependence on the step barrier;
        // LDS latency hides under the trans phase below)
        const int tn = t + 1;
        xv = *(const f16x4*)(xsB + ((tn >> 5) & 1) * 4224 + xrow + (tn & 31) * 8);

        cellpair(acc, 0, 1, wb);
        cellpair(acc, 2, 3, wb);
        STEP_BARRIER();
    };

    for (int t = 0; t < TSEQ; t += 2) {
        if ((t & (TCH - 1)) == 16) {
            const int c = t >> 5;                // current chunk
            if (c + 1 < NCH) {                   // stage chunk c+1 (regs arrived)
                f16x4 s0, s1;
                s0[0] = (_Float16)xn0.x; s0[1] = (_Float16)xn0.y;
                s0[2] = (_Float16)xn0.z; s0[3] = (_Float16)xn0.w;
                s1[0] = (_Float16)xn1.x; s1[1] = (_Float16)xn1.y;
                s1[2] = (_Float16)xn1.z; s1[3] = (_Float16)xn1.w;
                const int nb = (c + 1) & 1;
                xstage[0][nb][bb0][tf] = s0;
                xstage[1][nb][bb0][tf] = s1;
                if (c + 2 < NCH) {               // issue loads for chunk c+2
                    xn0 = *(const float4*)(xg0 + (size_t)(c + 2) * TCH * IDIM);
                    xn1 = *(const float4*)(xg1 + (size_t)(c + 2) * TCH * IDIM);
                }
            }
        }
        substep(t,     0);
        substep(t + 1, 1);
    }

    // ---- FC epilogue: final h in parity 0 (TRANS_511 wrote parity 0) ----
    #pragma unroll
    for (int q = 0; q < 4; ++q) {
        const int bat  = wvl * 4 + q;
        const int byte = (bat * 128 + lane * 2) ^ ((bat & 7) << 4);
        float hv = (float)*(const _Float16*)(hbG + byte);
        float partial = hv * wfc;
        #pragma unroll
        for (int off = 32; off > 0; off >>= 1)
            partial += __shfl_down(partial, off);
        if (lane == 0) out[b0 + grp * 16 + bat] = partial + bfc;
    }
}

extern "C" void kernel_launch(void* const* d_in, const int* in_sizes, int n_in,
                              void* d_out, int out_size, void* d_ws, size_t ws_size,
                              hipStream_t stream) {
    const float* x    = (const float*)d_in[0];
    const float* W_ih = (const float*)d_in[1];
    const float* W_hh = (const float*)d_in[2];
    const float* b_ih = (const float*)d_in[3];
    const float* b_hh = (const float*)d_in[4];
    const float* W_fc = (const float*)d_in[5];
    const float* b_fc = (const float*)d_in[6];
    float* out = (float*)d_out;

    const int B = in_sizes[0] / (TSEQ * IDIM);   // 8192
    lstm_fused<<<B / BPB, 512, 0, stream>>>(x, W_ih, W_hh, b_ih, b_hh, W_fc, b_fc, out);
}

// Round 14
// 291.544 us; speedup vs baseline: 1.0879x; 1.0879x over previous
//
#include <hip/hip_runtime.h>

// FireLSTM: x[8192,512,4] fp32 -> LSTM(H=64) -> FC(64->1), out[8192] fp32.
//
// Geometry (forced; R4-R13 sweep): 512 blocks x 256 thr (4 waves) = 2
// blocks/CU, 2 waves/SIMD. Block owns 16 batches; wave wv owns h-cols
// [16wv,16wv+16) for all 4 gate types: 12x mfma_f32_16x16x32_f16 per step
// (K=96=[h|x+bias|pad]); all 4 gate types of a cell land in one thread's regs
// -> activation + c/h update register-local. h double-buffered fp16
// XOR-swizzled LDS, ONE raw lgkm-only barrier/step (vmcnt never drained).
//
// R14 deltas vs R12 (LDS-pipe relief + chain ILP):
//  1. x LDS path REMOVED. Each thread global-loads its OWN x[b0+r][t] slice
//     (16 B) into an 8-deep register ring, prefetched 8 steps ahead (~13k cyc
//     >> HBM latency; x16 redundant reads are L1-absorbed and ride the idle
//     VMEM pipe, not the contended CU-shared LDS pipe: the post-barrier LDS
//     burst was ~430 cyc/CU/step). Ring statically indexed via 8x-unrolled
//     step loop. No xstage, no chunk staging, no per-step xv ds_read.
//  2. cellquad: both cellpairs fused, trans grouped by dependence level
//     (16 gate exp2 together -> algebra -> rcp -> et-exp2 -> rcp) for
//     maximum trans-latency overlap on the serial chain.
//  Kept: packed-f32 cell algebra, single-sided clamp, 7-trans merged-rcp
//  update, k-slot bias (68,69 vs A=1.0), zero-C operand, MFMA-only setprio,
//  s_sleep anti-phase nudge.

typedef float f32x4 __attribute__((ext_vector_type(4)));
typedef float f32x2 __attribute__((ext_vector_type(2)));
typedef _Float16 f16x8 __attribute__((ext_vector_type(8)));

#define TSEQ 512
#define IDIM 4
#define BPB 16
#define RING 8
#define L2E 1.44269504088896340736f

#if __has_builtin(__builtin_amdgcn_exp2f)
#define EX2(v) __builtin_amdgcn_exp2f(v)
#else
#define EX2(v) exp2f(v)
#endif
#define RCP(v) __builtin_amdgcn_rcpf(v)

// lgkmcnt(0) makes our ds_writes visible; s_barrier rendezvous. No vmcnt
// drain (ring loads float free); no sched_barrier (m141: order-pinning).
#define STEP_BARRIER() do {                                   \
    asm volatile("s_waitcnt lgkmcnt(0)" ::: "memory");        \
    __builtin_amdgcn_s_barrier();                             \
} while (0)

__global__ __launch_bounds__(256, 2) void lstm_fused(
    const float* __restrict__ x,
    const float* __restrict__ W_ih,
    const float* __restrict__ W_hh,
    const float* __restrict__ b_ih,
    const float* __restrict__ b_hh,
    const float* __restrict__ W_fc,
    const float* __restrict__ b_fc,
    float* __restrict__ out)
{
    __shared__ __align__(16) _Float16 hbuf[2][BPB * 64];   // 4 KB, XOR-swizzled

    const int tid  = threadIdx.x;
    const int lane = tid & 63;
    const int wv   = tid >> 6;
    const int b0   = blockIdx.x * BPB;
    const int r    = lane & 15;
    const int g16  = lane >> 4;

    // ---- B-fragments: 4 types x K=96, pre-scaled. k = ks*32 + 8*g16 + j.
    // ks=2: k=64..67 -> W_ih, k=68,69 -> bias hi/lo (vs A=1.0), k>=70 -> 0.
    f16x8 bfrag[4][3];
    #pragma unroll
    for (int t4 = 0; t4 < 4; ++t4) {
        const float sc = (t4 == 2) ? 2.0f * L2E : L2E;
        const int g = t4 * 64 + wv * 16 + r;
        #pragma unroll
        for (int ks = 0; ks < 2; ++ks) {
            const float* p = W_hh + g * 64 + ks * 32 + g16 * 8;
            f16x8 f;
            #pragma unroll
            for (int j = 0; j < 8; ++j) f[j] = (_Float16)(p[j] * sc);
            bfrag[t4][ks] = f;
        }
        f16x8 f;
        #pragma unroll
        for (int j = 0; j < 8; ++j) f[j] = (_Float16)0.0f;
        if (g16 == 0) {
            #pragma unroll
            for (int j = 0; j < 4; ++j) f[j] = (_Float16)(W_ih[g * IDIM + j] * sc);
            float biasf = (b_ih[g] + b_hh[g]) * sc;
            _Float16 hi = (_Float16)biasf;
            f[4] = hi;
            f[5] = (_Float16)(biasf - (float)hi);
        }
        bfrag[t4][2] = f;
    }
    const float wfc = W_fc[lane];
    const float bfc = b_fc[0];
    const f32x4 zero4 = {0.f, 0.f, 0.f, 0.f};

    float c_reg[4] = {0.f, 0.f, 0.f, 0.f};
    for (int i = tid; i < BPB * 64; i += 256) hbuf[0][i] = (_Float16)0.0f;

    // ---- x register ring: thread loads ITS OWN row (batch = r), 16 B/step,
    // prefetched RING steps ahead. Redundant x16 across consumers -> L1.
    const float* xgp = x + (size_t)(b0 + r) * (TSEQ * IDIM);
    float4 xring[RING];
    #pragma unroll
    for (int j = 0; j < RING; ++j)
        xring[j] = *(const float4*)(xgp + j * IDIM);

    __syncthreads();                       // hbuf zeroing visible

    // ---- anti-phase nudge (kept from R12's measured config) ----
    if (((blockIdx.x ^ (blockIdx.x >> 8)) & 1) != 0)
        __builtin_amdgcn_s_sleep(13);

    // ---- precomputed LDS byte offsets ----
    const int hbase = r * 128;
    const int hs0 = ((g16 + 0) << 4) ^ ((r & 7) << 4);
    const int hs1 = ((g16 + 4) << 4) ^ ((r & 7) << 4);
    int hw[4];
    #pragma unroll
    for (int q = 0; q < 4; ++q) {
        const int bat = 4 * g16 + q;
        hw[q] = (bat * 128 + (wv * 16 + r) * 2) ^ ((bat & 7) << 4);
    }
    char* hbB = (char*)&hbuf[0][0];

    // 4-cell update, level-grouped for trans-latency overlap.
    auto cellquad = [&](const f32x4* acc, char* wb) {
        const f32x2 one = {1.f, 1.f};
        // level 1: all 16 gate exp2 in flight together
        f32x2 ei[2], ef[2], eg[2], eo[2];
        #pragma unroll
        for (int p = 0; p < 2; ++p) {
            const int q0 = 2 * p, q1 = 2 * p + 1;
            ei[p][0] = EX2(-acc[0][q0]); ei[p][1] = EX2(-acc[0][q1]);
            ef[p][0] = EX2(-acc[1][q0]); ef[p][1] = EX2(-acc[1][q1]);
            eg[p][0] = EX2(-acc[2][q0]); eg[p][1] = EX2(-acc[2][q1]);
            eo[p][0] = EX2(-acc[3][q0]); eo[p][1] = EX2(-acc[3][q1]);
        }
        // level 2: packed algebra + c-denominator rcp
        f32x2 num[2], rd[2];
        #pragma unroll
        for (int p = 0; p < 2; ++p) {
            f32x2 A  = one + ei[p], F = one + ef[p];
            f32x2 Gp = one + eg[p], Gm = one - eg[p];
            f32x2 P2 = A * Gp;
            f32x2 cr = { c_reg[2 * p], c_reg[2 * p + 1] };
            num[p] = cr * P2 + Gm * F;
            f32x2 den = P2 * F;
            rd[p][0] = RCP(den[0]); rd[p][1] = RCP(den[1]);
        }
        // level 3: c, uc (single-sided clamp), et exp2
        f32x2 et[2];
        #pragma unroll
        for (int p = 0; p < 2; ++p) {
            f32x2 c = num[p] * rd[p];
            c_reg[2 * p]     = c[0];
            c_reg[2 * p + 1] = c[1];
            f32x2 uc = __builtin_elementwise_max(c * (2.0f * L2E),
                                                 f32x2{-60.f, -60.f});
            et[p][0] = EX2(-uc[0]); et[p][1] = EX2(-uc[1]);
        }
        // level 4: h = (1-et) * rcp((1+eo)(1+et)), write fp16
        #pragma unroll
        for (int p = 0; p < 2; ++p) {
            f32x2 hd = (one + eo[p]) * (one + et[p]);
            f32x2 rh; rh[0] = RCP(hd[0]); rh[1] = RCP(hd[1]);
            f32x2 h = (one - et[p]) * rh;
            *(_Float16*)(wb + hw[2 * p])     = (_Float16)h[0];
            *(_Float16*)(wb + hw[2 * p + 1]) = (_Float16)h[1];
        }
    };

    // one sub-step; P and slot are compile-time (8x-unrolled loop)
    auto substep = [&](int t, int P, int slot) {
        const char* rb = hbB + P * 2048;         // h_{t-1}
        char*       wb = hbB + (P ^ 1) * 2048;   // h_t
        f16x8 a0 = *(const f16x8*)(rb + hbase + hs0);
        f16x8 a1 = *(const f16x8*)(rb + hbase + hs1);
        float4 xf = xring[slot];
        f16x8 ax;
        ax[0] = (_Float16)xf.x; ax[1] = (_Float16)xf.y;
        ax[2] = (_Float16)xf.z; ax[3] = (_Float16)xf.w;
        ax[4] = (_Float16)1.0f; ax[5] = (_Float16)1.0f;   // bias slots (k=68,69)
        ax[6] = (_Float16)0.0f; ax[7] = (_Float16)0.0f;

        f32x4 acc[4];
        __builtin_amdgcn_s_setprio(1);
        #pragma unroll
        for (int t4 = 0; t4 < 4; ++t4) {
            f32x4 a;
            a = __builtin_amdgcn_mfma_f32_16x16x32_f16(a0, bfrag[t4][0], zero4, 0, 0, 0);
            a = __builtin_amdgcn_mfma_f32_16x16x32_f16(a1, bfrag[t4][1], a, 0, 0, 0);
            a = __builtin_amdgcn_mfma_f32_16x16x32_f16(ax, bfrag[t4][2], a, 0, 0, 0);
            acc[t4] = a;
        }
        __builtin_amdgcn_s_setprio(0);

        // refill ring slot for step t+RING (clamped reload of the last slice
        // when past the end -- loaded but never consumed). VMEM pipe; never
        // drained by the step barrier.
        {
            int tn = t + RING;
            if (tn > TSEQ - 1) tn = TSEQ - 1;
            xring[slot] = *(const float4*)(xgp + (size_t)tn * IDIM);
        }

        cellquad(acc, wb);
        STEP_BARRIER();
    };

    for (int t = 0; t < TSEQ; t += RING) {
        #pragma unroll
        for (int j = 0; j < RING; ++j)
            substep(t + j, j & 1, j);      // t%8==0 -> parity = j&1 (static)
    }

    // ---- FC epilogue: final h in parity 0 (TRANS_511 wrote parity 0) ----
    #pragma unroll
    for (int q = 0; q < 4; ++q) {
        const int bat  = wv * 4 + q;
        const int byte = (bat * 128 + lane * 2) ^ ((bat & 7) << 4);
        float hv = (float)*(const _Float16*)(hbB + byte);
        float partial = hv * wfc;
        #pragma unroll
        for (int off = 32; off > 0; off >>= 1)
            partial += __shfl_down(partial, off);
        if (lane == 0) out[b0 + bat] = partial + bfc;
    }
}

extern "C" void kernel_launch(void* const* d_in, const int* in_sizes, int n_in,
                              void* d_out, int out_size, void* d_ws, size_t ws_size,
                              hipStream_t stream) {
    const float* x    = (const float*)d_in[0];
    const float* W_ih = (const float*)d_in[1];
    const float* W_hh = (const float*)d_in[2];
    const float* b_ih = (const float*)d_in[3];
    const float* b_hh = (const float*)d_in[4];
    const float* W_fc = (const float*)d_in[5];
    const float* b_fc = (const float*)d_in[6];
    float* out = (float*)d_out;

    const int B = in_sizes[0] / (TSEQ * IDIM);   // 8192
    lstm_fused<<<B / BPB, 256, 0, stream>>>(x, W_ih, W_hh, b_ih, b_hh, W_fc, b_fc, out);
}

// Round 16
// 290.934 us; speedup vs baseline: 1.0902x; 1.0021x over previous
//
#include <hip/hip_runtime.h>

// FireLSTM: x[8192,512,4] fp32 -> LSTM(H=64) -> FC(64->1), out[8192] fp32.
//
// Geometry (forced; R4-R14 sweep): 512 blocks x 256 thr (4 waves) = 2
// blocks/CU, 2 waves/SIMD. Block owns 16 batches; wave wv owns h-cols
// [16wv,16wv+16) for all 4 gate types: 12x mfma_f32_16x16x32_f16 per step
// (K=96=[h|x+bias|pad]); all 4 gate types of a cell land in one thread's regs
// -> activation + c/h update register-local. h double-buffered fp16
// XOR-swizzled LDS, ONE raw lgkm-only barrier/step (vmcnt never drained).
// x: per-thread global register ring (no LDS), prefetched RING steps ahead.
//
// R16 = R15 with the compile fix: __builtin_amdgcn_cvt_pkrtz returns
// __fp16x2 (not _Float16x2) -- receive as __fp16 vector, bit-cast.
//  1. Packed x->fp16 via cvt_pkrtz (2 insts vs 4 RTE cvts + packs); ax
//     assembled by shufflevector against a persistent {1,1,0,0} tail.
//  2. c-state pre-scaled: cs = 2*log2e*c. Gm2 = 2L2E - eg*2L2E (pk_fma),
//     cs' = (cs*P2 + Gm2*F)*rcp(P2*F), uc = max(cs,-60).
//  Kept: level-grouped cellquad (5 exp2 + 2 rcp per cell), k-slot bias
//  (68,69 vs A=1.0), zero-C operand, MFMA-only setprio, s_sleep nudge,
//  single-sided clamp, 8-deep x ring with clamped refill.

typedef float f32x4 __attribute__((ext_vector_type(4)));
typedef float f32x2 __attribute__((ext_vector_type(2)));
typedef _Float16 f16x8 __attribute__((ext_vector_type(8)));
typedef _Float16 f16x4 __attribute__((ext_vector_type(4)));
typedef _Float16 f16x2 __attribute__((ext_vector_type(2)));
typedef __fp16   h16x2 __attribute__((ext_vector_type(2)));   // cvt_pkrtz ret type

#define TSEQ 512
#define IDIM 4
#define BPB 16
#define RING 8
#define L2E 1.44269504088896340736f
#define TWO_L2E (2.0f * L2E)

#if __has_builtin(__builtin_amdgcn_exp2f)
#define EX2(v) __builtin_amdgcn_exp2f(v)
#else
#define EX2(v) exp2f(v)
#endif
#define RCP(v) __builtin_amdgcn_rcpf(v)

// lgkmcnt(0) makes our ds_writes visible; s_barrier rendezvous. No vmcnt
// drain (ring loads float free); no sched_barrier (m141: order-pinning).
#define STEP_BARRIER() do {                                   \
    asm volatile("s_waitcnt lgkmcnt(0)" ::: "memory");        \
    __builtin_amdgcn_s_barrier();                             \
} while (0)

__device__ __forceinline__ f16x2 cvt_pk(float a, float b) {
    h16x2 v = __builtin_amdgcn_cvt_pkrtz(a, b);
    return __builtin_bit_cast(f16x2, v);
}

__global__ __launch_bounds__(256, 2) void lstm_fused(
    const float* __restrict__ x,
    const float* __restrict__ W_ih,
    const float* __restrict__ W_hh,
    const float* __restrict__ b_ih,
    const float* __restrict__ b_hh,
    const float* __restrict__ W_fc,
    const float* __restrict__ b_fc,
    float* __restrict__ out)
{
    __shared__ __align__(16) _Float16 hbuf[2][BPB * 64];   // 4 KB, XOR-swizzled

    const int tid  = threadIdx.x;
    const int lane = tid & 63;
    const int wv   = tid >> 6;
    const int b0   = blockIdx.x * BPB;
    const int r    = lane & 15;
    const int g16  = lane >> 4;

    // ---- B-fragments: 4 types x K=96, pre-scaled. k = ks*32 + 8*g16 + j.
    // ks=2: k=64..67 -> W_ih, k=68,69 -> bias hi/lo (vs A=1.0), k>=70 -> 0.
    f16x8 bfrag[4][3];
    #pragma unroll
    for (int t4 = 0; t4 < 4; ++t4) {
        const float sc = (t4 == 2) ? TWO_L2E : L2E;
        const int g = t4 * 64 + wv * 16 + r;
        #pragma unroll
        for (int ks = 0; ks < 2; ++ks) {
            const float* p = W_hh + g * 64 + ks * 32 + g16 * 8;
            f16x8 f;
            #pragma unroll
            for (int j = 0; j < 8; ++j) f[j] = (_Float16)(p[j] * sc);
            bfrag[t4][ks] = f;
        }
        f16x8 f;
        #pragma unroll
        for (int j = 0; j < 8; ++j) f[j] = (_Float16)0.0f;
        if (g16 == 0) {
            #pragma unroll
            for (int j = 0; j < 4; ++j) f[j] = (_Float16)(W_ih[g * IDIM + j] * sc);
            float biasf = (b_ih[g] + b_hh[g]) * sc;
            _Float16 hi = (_Float16)biasf;
            f[4] = hi;
            f[5] = (_Float16)(biasf - (float)hi);
        }
        bfrag[t4][2] = f;
    }
    const float wfc = W_fc[lane];
    const float bfc = b_fc[0];
    const f32x4 zero4 = {0.f, 0.f, 0.f, 0.f};
    // bias/pad K-slots as a persistent packed half-vector {1,1,0,0}
    const f16x4 axtail = { (_Float16)1.0f, (_Float16)1.0f,
                           (_Float16)0.0f, (_Float16)0.0f };

    float cs_reg[4] = {0.f, 0.f, 0.f, 0.f};   // cs = 2*log2e * c
    for (int i = tid; i < BPB * 64; i += 256) hbuf[0][i] = (_Float16)0.0f;

    // ---- x register ring: thread loads ITS OWN row (batch = r), 16 B/step,
    // prefetched RING steps ahead. Redundant x16 across consumers -> L1.
    const float* xgp = x + (size_t)(b0 + r) * (TSEQ * IDIM);
    float4 xring[RING];
    #pragma unroll
    for (int j = 0; j < RING; ++j)
        xring[j] = *(const float4*)(xgp + j * IDIM);

    __syncthreads();                       // hbuf zeroing visible

    // ---- anti-phase nudge (kept from R12's measured config) ----
    if (((blockIdx.x ^ (blockIdx.x >> 8)) & 1) != 0)
        __builtin_amdgcn_s_sleep(13);

    // ---- precomputed LDS byte offsets ----
    const int hbase = r * 128;
    const int hs0 = ((g16 + 0) << 4) ^ ((r & 7) << 4);
    const int hs1 = ((g16 + 4) << 4) ^ ((r & 7) << 4);
    int hw[4];
    #pragma unroll
    for (int q = 0; q < 4; ++q) {
        const int bat = 4 * g16 + q;
        hw[q] = (bat * 128 + (wv * 16 + r) * 2) ^ ((bat & 7) << 4);
    }
    char* hbB = (char*)&hbuf[0][0];

    // 4-cell update, level-grouped for trans-latency overlap. State is cs.
    auto cellquad = [&](const f32x4* acc, char* wb) {
        const f32x2 one = {1.f, 1.f};
        const f32x2 two_l2e = {TWO_L2E, TWO_L2E};
        // level 1: all 16 gate exp2 in flight together
        f32x2 ei[2], ef[2], eg[2], eo[2];
        #pragma unroll
        for (int p = 0; p < 2; ++p) {
            const int q0 = 2 * p, q1 = 2 * p + 1;
            ei[p][0] = EX2(-acc[0][q0]); ei[p][1] = EX2(-acc[0][q1]);
            ef[p][0] = EX2(-acc[1][q0]); ef[p][1] = EX2(-acc[1][q1]);
            eg[p][0] = EX2(-acc[2][q0]); eg[p][1] = EX2(-acc[2][q1]);
            eo[p][0] = EX2(-acc[3][q0]); eo[p][1] = EX2(-acc[3][q1]);
        }
        // level 2: packed algebra + cs-denominator rcp
        f32x2 num[2], rd[2];
        #pragma unroll
        for (int p = 0; p < 2; ++p) {
            f32x2 A  = one + ei[p], F = one + ef[p];
            f32x2 Gp = one + eg[p];
            f32x2 Gm2 = two_l2e - eg[p] * two_l2e;   // 2L2E*(1-eg), one pk_fma
            f32x2 P2 = A * Gp;
            f32x2 cr = { cs_reg[2 * p], cs_reg[2 * p + 1] };
            num[p] = cr * P2 + Gm2 * F;
            f32x2 den = P2 * F;
            rd[p][0] = RCP(den[0]); rd[p][1] = RCP(den[1]);
        }
        // level 3: cs, uc (single-sided clamp), et exp2
        f32x2 et[2];
        #pragma unroll
        for (int p = 0; p < 2; ++p) {
            f32x2 cs = num[p] * rd[p];
            cs_reg[2 * p]     = cs[0];
            cs_reg[2 * p + 1] = cs[1];
            f32x2 uc = __builtin_elementwise_max(cs, f32x2{-60.f, -60.f});
            et[p][0] = EX2(-uc[0]); et[p][1] = EX2(-uc[1]);
        }
        // level 4: h = (1-et) * rcp((1+eo)(1+et)), write fp16
        #pragma unroll
        for (int p = 0; p < 2; ++p) {
            f32x2 hd = (one + eo[p]) * (one + et[p]);
            f32x2 rh; rh[0] = RCP(hd[0]); rh[1] = RCP(hd[1]);
            f32x2 h = (one - et[p]) * rh;
            *(_Float16*)(wb + hw[2 * p])     = (_Float16)h[0];
            *(_Float16*)(wb + hw[2 * p + 1]) = (_Float16)h[1];
        }
    };

    // one sub-step; P and slot are compile-time (8x-unrolled loop)
    auto substep = [&](int t, int P, int slot) {
        const char* rb = hbB + P * 2048;         // h_{t-1}
        char*       wb = hbB + (P ^ 1) * 2048;   // h_t
        f16x8 a0 = *(const f16x8*)(rb + hbase + hs0);
        f16x8 a1 = *(const f16x8*)(rb + hbase + hs1);
        float4 xf = xring[slot];
        // packed RTZ conversion: 2 insts, then assemble with constant tail
        f16x2 xlo = cvt_pk(xf.x, xf.y);
        f16x2 xhi = cvt_pk(xf.z, xf.w);
        f16x4 xq  = __builtin_shufflevector(xlo, xhi, 0, 1, 2, 3);
        f16x8 ax  = __builtin_shufflevector(xq, axtail, 0, 1, 2, 3, 4, 5, 6, 7);

        f32x4 acc[4];
        __builtin_amdgcn_s_setprio(1);
        #pragma unroll
        for (int t4 = 0; t4 < 4; ++t4) {
            f32x4 a;
            a = __builtin_amdgcn_mfma_f32_16x16x32_f16(a0, bfrag[t4][0], zero4, 0, 0, 0);
            a = __builtin_amdgcn_mfma_f32_16x16x32_f16(a1, bfrag[t4][1], a, 0, 0, 0);
            a = __builtin_amdgcn_mfma_f32_16x16x32_f16(ax, bfrag[t4][2], a, 0, 0, 0);
            acc[t4] = a;
        }
        __builtin_amdgcn_s_setprio(0);

        // refill ring slot for step t+RING (clamped; VMEM pipe, never drained)
        {
            int tn = t + RING;
            if (tn > TSEQ - 1) tn = TSEQ - 1;
            xring[slot] = *(const float4*)(xgp + (size_t)tn * IDIM);
        }

        cellquad(acc, wb);
        STEP_BARRIER();
    };

    for (int t = 0; t < TSEQ; t += RING) {
        #pragma unroll
        for (int j = 0; j < RING; ++j)
            substep(t + j, j & 1, j);      // t%8==0 -> parity = j&1 (static)
    }

    // ---- FC epilogue: final h in parity 0 (TRANS_511 wrote parity 0) ----
    #pragma unroll
    for (int q = 0; q < 4; ++q) {
        const int bat  = wv * 4 + q;
        const int byte = (bat * 128 + lane * 2) ^ ((bat & 7) << 4);
        float hv = (float)*(const _Float16*)(hbB + byte);
        float partial = hv * wfc;
        #pragma unroll
        for (int off = 32; off > 0; off >>= 1)
            partial += __shfl_down(partial, off);
        if (lane == 0) out[b0 + bat] = partial + bfc;
    }
}

extern "C" void kernel_launch(void* const* d_in, const int* in_sizes, int n_in,
                              void* d_out, int out_size, void* d_ws, size_t ws_size,
                              hipStream_t stream) {
    const float* x    = (const float*)d_in[0];
    const float* W_ih = (const float*)d_in[1];
    const float* W_hh = (const float*)d_in[2];
    const float* b_ih = (const float*)d_in[3];
    const float* b_hh = (const float*)d_in[4];
    const float* W_fc = (const float*)d_in[5];
    const float* b_fc = (const float*)d_in[6];
    float* out = (float*)d_out;

    const int B = in_sizes[0] / (TSEQ * IDIM);   // 8192
    lstm_fused<<<B / BPB, 256, 0, stream>>>(x, W_ih, W_hh, b_ih, b_hh, W_fc, b_fc, out);
}